// Round 4
// baseline (804.898 us; speedup 1.0000x reference)
//
#include <hip/hip_runtime.h>
#include <hip/hip_bf16.h>
#include <stdint.h>

#define NTOK 4096
#define EMBD 1024
#define NEXP 8
#define HIDD 2048
#define NPAIR (NTOK * 2)

typedef __attribute__((ext_vector_type(8))) __bf16 bf16x8;
typedef __attribute__((ext_vector_type(4))) float f32x4;

union V16 { uint4 u; bf16x8 b; };

__device__ __forceinline__ uint16_t f2bf(float f) {
    uint32_t u = __float_as_uint(f);
    return (uint16_t)((u + 0x7FFFu + ((u >> 16) & 1u)) >> 16);
}
__device__ __forceinline__ uint32_t pk2bf(float a, float b) {
    return (uint32_t)f2bf(a) | ((uint32_t)f2bf(b) << 16);
}
__device__ __forceinline__ float bf2f(uint16_t u) {
    return __uint_as_float(((uint32_t)u) << 16);
}
__device__ __forceinline__ void gl_lds16(const uint16_t* g, uint16_t* l) {
    __builtin_amdgcn_global_load_lds(
        (const __attribute__((address_space(1))) void*)g,
        (__attribute__((address_space(3))) void*)l, 16, 0, 0);
}

// ---- router (+ x cast fused): one wave per token ----
__global__ __launch_bounds__(64) void router_kernel(const float* __restrict__ x,
                                                    const float* __restrict__ Wr,
                                                    const float* __restrict__ br,
                                                    uint16_t* __restrict__ xb,
                                                    int* __restrict__ counts,
                                                    int* __restrict__ pair_e,
                                                    float* __restrict__ pair_p) {
    int tok = blockIdx.x;
    int lane = threadIdx.x;
    const float* xr = x + (size_t)tok * EMBD;
    uint16_t* xbr = xb + (size_t)tok * EMBD;
    float acc[NEXP];
#pragma unroll
    for (int e = 0; e < NEXP; e++) acc[e] = 0.f;
    for (int d = lane; d < EMBD; d += 64) {
        float xv = xr[d];
        xbr[d] = f2bf(xv);
#pragma unroll
        for (int e = 0; e < NEXP; e++) acc[e] += xv * Wr[d * NEXP + e];
    }
#pragma unroll
    for (int e = 0; e < NEXP; e++) {
#pragma unroll
        for (int off = 32; off > 0; off >>= 1)
            acc[e] += __shfl_down(acc[e], off, 64);
    }
    if (lane == 0) {
        float lg[NEXP];
#pragma unroll
        for (int e = 0; e < NEXP; e++) lg[e] = acc[e] + br[e];
        int e0 = 0;
#pragma unroll
        for (int e = 1; e < NEXP; e++) if (lg[e] > lg[e0]) e0 = e;
        int e1 = (e0 == 0) ? 1 : 0;
#pragma unroll
        for (int e = 0; e < NEXP; e++) if (e != e0 && lg[e] > lg[e1]) e1 = e;
        float mx = lg[0];
#pragma unroll
        for (int e = 1; e < NEXP; e++) mx = fmaxf(mx, lg[e]);
        float s = 0.f, p[NEXP];
#pragma unroll
        for (int e = 0; e < NEXP; e++) { p[e] = __expf(lg[e] - mx); s += p[e]; }
        float inv = 1.f / s;
        pair_e[tok * 2 + 0] = e0; pair_p[tok * 2 + 0] = p[e0] * inv;
        pair_e[tok * 2 + 1] = e1; pair_p[tok * 2 + 1] = p[e1] * inv;
        atomicAdd(&counts[e0], 1);
        atomicAdd(&counts[e1], 1);
    }
}

// ---- scatter (computes offsets locally from counts) ----
__global__ __launch_bounds__(256) void scatter_kernel(const int* __restrict__ pair_e,
                                                      const int* __restrict__ counts,
                                                      int* __restrict__ cursors,
                                                      int* __restrict__ toklist,
                                                      int* __restrict__ posmap) {
    int i = blockIdx.x * 256 + threadIdx.x;  // pair index
    int e = pair_e[i];
    int offs = 0;
    for (int j = 0; j < NEXP; j++) offs += (j < e) ? counts[j] : 0;
    int pos = offs + atomicAdd(&cursors[e], 1);
    toklist[pos] = i >> 1;
    posmap[i] = pos;
}

// ---- grouped GEMM: 128x128 tile, BK=32, 4 waves, 4x4 MFMA/wave.
// A: bf16 [rows][KDIM], staged via global_load_lds (XOR-swizzled LDS, conflict-free).
// B: fp32 weights [E][KDIM][NDIM] staged DIRECTLY: per-thread 4k x 4n register
//    block -> f2bf pack -> ds_write_b64 into padded LDS (stride 36 u16 = 72B),
//    with register prefetch of the next K-block's B during the MFMA phase.
//    This removes the separate transpose-cast pass (402 MB HBM round trip).
template <int KDIM, int NDIM, bool GATHER_A, bool RELU>
__global__ __launch_bounds__(256) void gemm_kernel(
    const uint16_t* __restrict__ Abase, const float* __restrict__ Wbase,
    const float* __restrict__ bbase, uint16_t* __restrict__ Out,
    const int* __restrict__ counts, const int* __restrict__ toklist) {
    int e = blockIdx.z;
    int offs = 0;
    for (int j = 0; j < NEXP; j++) offs += (j < e) ? counts[j] : 0;
    int n_e = counts[e];
    int m0 = blockIdx.y * 128;
    if (m0 >= n_e) return;
    int n0 = blockIdx.x * 128;
    const float* W = Wbase + (size_t)e * KDIM * NDIM;

    __shared__ uint16_t As[128 * 32];      // XOR-swizzled, no pad (global_load_lds)
    __shared__ uint16_t Bs[128 * 36];      // padded rows: 32 k + 4 pad (72B, b64-aligned)

    int tid = threadIdx.x;
    int lane = tid & 63;
    int wave = tid >> 6;

    // ---- A staging pointers (global_load_lds, 16B/lane) ----
    int sr = tid >> 2;
    int ss = tid & 3;
    const uint16_t* arp[2];
#pragma unroll
    for (int p = 0; p < 2; p++) {
        int r = p * 64 + sr;
        int gs = ss ^ ((r >> 1) & 3);
        int grow;
        if (GATHER_A) {
            int idx = m0 + r;
            if (idx >= n_e) idx = 0;
            grow = toklist[offs + idx];
        } else {
            grow = offs + m0 + r;  // rows >= n_e read garbage; never stored
        }
        arp[p] = Abase + (size_t)grow * KDIM + gs * 8;
    }
    uint16_t* alds[2] = { &As[wave * 512], &As[2048 + wave * 512] };

    // ---- B staging: thread -> 4k x 4n block ----
    int nq = tid & 31;           // n = nq*4 .. +3
    int kq = tid >> 5;           // k = kq*4 .. +3
    const float* Wp = W + (size_t)(kq * 4) * NDIM + n0 + nq * 4;
    uint16_t* bwp = &Bs[(nq * 4) * 36 + kq * 4];

    // ---- fragment read addresses ----
    int wm = (wave >> 1) * 64;
    int wn = (wave & 1) * 64;
    int l16 = lane & 15, qd = lane >> 4;
    const uint16_t* afp[4];
    const uint16_t* bfp[4];
#pragma unroll
    for (int t = 0; t < 4; t++) {
        int ar = wm + t * 16 + l16;
        afp[t] = &As[ar * 32 + (qd ^ ((ar >> 1) & 3)) * 8];
        int br = wn + t * 16 + l16;
        bfp[t] = &Bs[br * 36 + qd * 8];
    }

    f32x4 acc[4][4];
    f32x4 zero = {0.f, 0.f, 0.f, 0.f};
#pragma unroll
    for (int i = 0; i < 4; i++)
#pragma unroll
        for (int j = 0; j < 4; j++) acc[i][j] = zero;

    // preload first B K-block into registers
    float4 breg[4];
#pragma unroll
    for (int j = 0; j < 4; j++)
        breg[j] = *(const float4*)(Wp + (size_t)j * NDIM);

    for (int kb = 0; kb < KDIM; kb += 32) {
        // A: async global->LDS
#pragma unroll
        for (int p = 0; p < 2; p++) gl_lds16(arp[p] + kb, alds[p]);
        // B: convert current register block, write transposed to LDS
#pragma unroll
        for (int i = 0; i < 4; i++) {
            uint2 d;
            d.x = pk2bf(breg[0].x, breg[1].x);
            d.y = pk2bf(breg[2].x, breg[3].x);
            *(uint2*)(bwp + i * 36) = d;
            // rotate: shift each float4 down one lane (x<-y<-z<-w) via rebuild
            float4 t0 = breg[0], t1 = breg[1], t2 = breg[2], t3 = breg[3];
            breg[0] = make_float4(t0.y, t0.z, t0.w, t0.x);
            breg[1] = make_float4(t1.y, t1.z, t1.w, t1.x);
            breg[2] = make_float4(t2.y, t2.z, t2.w, t2.x);
            breg[3] = make_float4(t3.y, t3.z, t3.w, t3.x);
        }
        // prefetch next B K-block (lands during MFMA phase)
        int kbn = (kb + 32 < KDIM) ? kb + 32 : 0;
        float4 bnext[4];
#pragma unroll
        for (int j = 0; j < 4; j++)
            bnext[j] = *(const float4*)(Wp + (size_t)(kbn + j) * NDIM);
        __syncthreads();
        V16 af[4], bf[4];
#pragma unroll
        for (int t = 0; t < 4; t++) {
            af[t].u = *(const uint4*)(afp[t]);
            uint2 lo = *(const uint2*)(bfp[t]);
            uint2 hi = *(const uint2*)(bfp[t] + 4);
            bf[t].u = make_uint4(lo.x, lo.y, hi.x, hi.y);
        }
#pragma unroll
        for (int i = 0; i < 4; i++)
#pragma unroll
            for (int j = 0; j < 4; j++)
                acc[i][j] = __builtin_amdgcn_mfma_f32_16x16x32_bf16(
                    af[i].b, bf[j].b, acc[i][j], 0, 0, 0);
        __syncthreads();
#pragma unroll
        for (int j = 0; j < 4; j++) breg[j] = bnext[j];
    }

    // epilogue: C/D layout col=lane&15, row=(lane>>4)*4+reg
    const float* bias = bbase + (size_t)e * NDIM;
    int mrem = n_e - m0;
#pragma unroll
    for (int i = 0; i < 4; i++) {
        int rb = wm + i * 16 + qd * 4;
#pragma unroll
        for (int j = 0; j < 4; j++) {
            int col = n0 + wn + j * 16 + l16;
            float bv = bias[col];
#pragma unroll
            for (int r = 0; r < 4; r++) {
                int lr = rb + r;
                if (lr < mrem) {
                    float v = acc[i][j][r] + bv;
                    if (RELU) v = fmaxf(v, 0.f);
                    Out[(size_t)(offs + m0 + lr) * NDIM + col] = f2bf(v);
                }
            }
        }
    }
}

// ---- combine: out[t] = p0*y[pos0] + p1*y[pos1] ----
__global__ __launch_bounds__(256) void combine_kernel(const uint16_t* __restrict__ y,
                                                      const int* __restrict__ posmap,
                                                      const float* __restrict__ pair_p,
                                                      float* __restrict__ out) {
    int t = blockIdx.x;
    int d4 = threadIdx.x;
    int p0 = posmap[t * 2], p1 = posmap[t * 2 + 1];
    float w0 = pair_p[t * 2], w1 = pair_p[t * 2 + 1];
    ushort4 a = ((const ushort4*)(y + (size_t)p0 * EMBD))[d4];
    ushort4 b = ((const ushort4*)(y + (size_t)p1 * EMBD))[d4];
    float4 o;
    o.x = w0 * bf2f(a.x) + w1 * bf2f(b.x);
    o.y = w0 * bf2f(a.y) + w1 * bf2f(b.y);
    o.z = w0 * bf2f(a.z) + w1 * bf2f(b.z);
    o.w = w0 * bf2f(a.w) + w1 * bf2f(b.w);
    ((float4*)(out + (size_t)t * EMBD))[d4] = o;
}

extern "C" void kernel_launch(void* const* d_in, const int* in_sizes, int n_in,
                              void* d_out, int out_size, void* d_ws, size_t ws_size,
                              hipStream_t stream) {
    const float* x  = (const float*)d_in[0];
    const float* Wr = (const float*)d_in[1];
    const float* br = (const float*)d_in[2];
    const float* W1 = (const float*)d_in[3];
    const float* b1 = (const float*)d_in[4];
    const float* Wg = (const float*)d_in[5];
    const float* bg = (const float*)d_in[6];
    const float* W2 = (const float*)d_in[7];
    const float* b2 = (const float*)d_in[8];
    float* out = (float*)d_out;

    char* ws = (char*)d_ws;
    uint16_t* xb = (uint16_t*)ws;                    //  8 MB
    uint16_t* h  = (uint16_t*)(ws + (8ull << 20));   // 32 MB; yb aliases (h dead at L3)
    uint16_t* yb = h;
    uint16_t* g  = (uint16_t*)(ws + (40ull << 20));  // 32 MB
    int* meta = (int*)(ws + (72ull << 20));
    int*   counts  = meta;                    // 8
    int*   cursors = meta + 8;                // 8
    int*   pair_e  = meta + 16;               // NPAIR
    int*   toklist = meta + 16 + NPAIR;       // NPAIR
    int*   posmap  = meta + 16 + 2 * NPAIR;   // NPAIR
    float* pair_p  = (float*)(meta + 16 + 3 * NPAIR);  // NPAIR

    hipMemsetAsync(counts, 0, 16 * sizeof(int), stream);

    router_kernel<<<NTOK, 64, 0, stream>>>(x, Wr, br, xb, counts, pair_e, pair_p);
    scatter_kernel<<<NPAIR / 256, 256, 0, stream>>>(pair_e, counts, cursors, toklist, posmap);

    // layer1: [n_e,1024] x [1024,2048]
    gemm_kernel<EMBD, HIDD, true, false>
        <<<dim3(HIDD / 128, NTOK / 128, NEXP), 256, 0, stream>>>(
            xb, W1, b1, h, counts, toklist);
    // layer2: relu([n_e,2048] x [2048,2048])
    gemm_kernel<HIDD, HIDD, false, true>
        <<<dim3(HIDD / 128, NTOK / 128, NEXP), 256, 0, stream>>>(
            h, Wg, bg, g, counts, toklist);
    // layer3: [n_e,2048] x [2048,1024]
    gemm_kernel<HIDD, EMBD, false, false>
        <<<dim3(EMBD / 128, NTOK / 128, NEXP), 256, 0, stream>>>(
            g, W2, b2, yb, counts, toklist);
    combine_kernel<<<NTOK, 256, 0, stream>>>(yb, posmap, pair_p, out);
}